// Round 7
// baseline (589.552 us; speedup 1.0000x reference)
//
#include <hip/hip_runtime.h>
#include <stdint.h>

typedef unsigned short u16;
typedef __bf16 bf16x8 __attribute__((ext_vector_type(8)));
typedef float f32x4 __attribute__((ext_vector_type(4)));
typedef unsigned short u16x8 __attribute__((ext_vector_type(8)));
typedef unsigned short u16x4 __attribute__((ext_vector_type(4)));

__device__ __forceinline__ float b2f(u16 b) {
    return __uint_as_float(((unsigned)b) << 16);
}
__device__ __forceinline__ u16 f2b(float f) {
    unsigned u = __float_as_uint(f);
    unsigned r = (u + 0x7fffu + ((u >> 16) & 1u)) >> 16;  // RNE
    return (u16)r;
}

#define GLDS16(g, l) __builtin_amdgcn_global_load_lds(                        \
    (const __attribute__((address_space(1))) void*)(g),                       \
    (__attribute__((address_space(3))) void*)(l), 16, 0, 0)

// ---------------------------------------------------------------------------
// 256x256-tile GEMM, 2 steps per K-tile, full-K-half register pipeline.
// C = epilogue(A @ Bt^T); A[M,K], Bt[N,K] bf16 row-major. 512 thr = 8 waves
// (2M x 4N); per-wave C = 128x64. BK=64 as 2 K-halves stored [256][32] elem
// (64B rows; wave-wide ds_read_b128 covers dense 1KB -> conflict-free).
//
// Steady state, tile t in buffer BUF (tiles alternate buffers):
//  S1: ds Y <- (BUF,kk1) [12 b128] ; stage t+1.h1 -> BUF^1.kk1 [4 gld]
//      LGK(12) (drains X's reads, issued one full step ago -> ~free)
//      32 MFMA on X (kk0) ; VMC(4)+BAR   [guards t+1.h0 for S2's reads]
//  S2: ds X <- (BUF^1,kk0 = t+1.kk0) [12] ; stage t+2.h0 -> BUF.kk0 [4]
//      LGK(12) (drains Y) ; 32 MFMA on Y (kk1) ; VMC(4)+BAR [guards t+1.h1]
// Ledger: at each checkpoint exactly 8 gloads outstanding, keep newest 4;
// every staged half has a full-step (>=1200cy) flight before first read.
// WAR: stage into a region only after the LGK that drained its readers plus
// one barrier.  Prologue stages t0.h0,t0.h1,t1.h0 (vmcnt 8 then 4); tail:
// PEN tile ends VMC(0), LAST tile needs no sync.  NT must be even, >= 4.
// OUT_MODE: 0 = bf16 [.,N], 1 = f32 [.,N], 2 = bf16 V^T scatter
//           (b = row>>12, Vt[b][col][row&4095], batch stride 1<<22).
// ---------------------------------------------------------------------------
template<int HAS_BIAS, int RELU, int HAS_RES, int OUT_MODE>
__device__ __forceinline__ void gemm10_body(
    const u16* __restrict__ A, const u16* __restrict__ Bt,
    const float* __restrict__ bias, const float* __restrict__ res,
    void* __restrict__ Cout, int N, int K,
    long sA, long sB, long sC, long sR, float scale)
{
    __shared__ u16 smem[65536];   // 128 KiB: A [buf][kk] 16KB x4, then B x4

    // chunked XCD swizzle (bijective; all grids here have nwg % 8 == 0)
    const long nwg = (long)gridDim.x * gridDim.y * gridDim.z;
    long gid = ((long)blockIdx.z * gridDim.y + blockIdx.y) * gridDim.x + blockIdx.x;
    long logical = (nwg % 8 == 0) ? (gid & 7) * (nwg >> 3) + (gid >> 3) : gid;
    const int bx = (int)(logical % gridDim.x);
    long tmp = logical / gridDim.x;
    const int by = (int)(tmp % gridDim.y);
    const int bz = (int)(tmp / gridDim.y);

    A  += (long)bz * sA;
    Bt += (long)bz * sB;

    const int tid  = threadIdx.x;
    const int lane = tid & 63, wid = tid >> 6;
    const int wm   = wid >> 2, wn = wid & 3;
    const int lr   = lane & 15, lk = lane >> 4;
    const long m0  = (long)by * 256;
    const long n0  = (long)bx * 256;
    const int  NT  = K >> 6;          // even (K = 1024 or 4096)

    const u16* gA0 = A  + (m0 + (tid >> 2)) * (long)K + (tid & 3) * 8;
    const u16* gB0 = Bt + (n0 + (tid >> 2)) * (long)K + (tid & 3) * 8;
    const u16* gA1 = gA0 + 128L * K;
    const u16* gB1 = gB0 + 128L * K;
    const int wdst = (tid & ~63) * 8;   // u16 elems

#define STA(bufn, kk, kof) do {                                               \
    GLDS16(gA0 + (kof) + (kk) * 32, &smem[(bufn)*16384 + (kk)*8192 + wdst]);  \
    GLDS16(gA1 + (kof) + (kk) * 32, &smem[(bufn)*16384 + (kk)*8192 + wdst + 4096]); } while (0)
#define STB(bufn, kk, kof) do {                                               \
    GLDS16(gB0 + (kof) + (kk) * 32, &smem[32768 + (bufn)*16384 + (kk)*8192 + wdst]); \
    GLDS16(gB1 + (kof) + (kk) * 32, &smem[32768 + (bufn)*16384 + (kk)*8192 + wdst + 4096]); } while (0)

    const int raOff = (wm * 128 + lr) * 32 + lk * 8;   // + i*512 per A-frag
    const int rbOff = (wn * 64  + lr) * 32 + lk * 8;   // + j*512 per B-frag

#define DSA8(dst, BUF, kk) do { _Pragma("unroll")                             \
    for (int i = 0; i < 8; ++i)                                               \
        dst[i] = *(const bf16x8*)&smem[(BUF)*16384 + (kk)*8192 + raOff + i*512]; } while (0)
#define DSB4(dst, BUF, kk) do { _Pragma("unroll")                             \
    for (int j = 0; j < 4; ++j)                                               \
        dst[j] = *(const bf16x8*)&smem[32768 + (BUF)*16384 + (kk)*8192 + rbOff + j*512]; } while (0)

#define LGK(n) do { asm volatile("s_waitcnt lgkmcnt(" #n ")" ::: "memory");   \
                    __builtin_amdgcn_sched_barrier(0); } while (0)
#define CKPT(n) do { asm volatile("s_waitcnt vmcnt(" #n ")" ::: "memory");    \
    __builtin_amdgcn_s_barrier(); __builtin_amdgcn_sched_barrier(0); } while (0)

#define MFM32(A_, B_) do { __builtin_amdgcn_s_setprio(1); _Pragma("unroll")   \
    for (int i = 0; i < 8; ++i) _Pragma("unroll")                             \
        for (int j = 0; j < 4; ++j)                                           \
            acc[i][j] = __builtin_amdgcn_mfma_f32_16x16x32_bf16(              \
                A_[i], B_[j], acc[i][j], 0, 0, 0);                            \
    __builtin_amdgcn_s_setprio(0); } while (0)

// Full tile t in buffer BUF; stages t+1.h1 (S1) and t+2.h0 (S2).
#define TILE_FULL(BUF, kof1, kof2) do {                                       \
    DSA8(aY, BUF, 1);  DSB4(bY, BUF, 1);                                      \
    STA((BUF)^1, 1, kof1);  STB((BUF)^1, 1, kof1);                            \
    LGK(12);  MFM32(aX, bX);  CKPT(4);                                        \
    DSA8(aX, (BUF)^1, 0);  DSB4(bX, (BUF)^1, 0);                              \
    STA(BUF, 0, kof2);  STB(BUF, 0, kof2);                                    \
    LGK(12);  MFM32(aY, bY);  CKPT(4);                                        \
} while (0)

// Penultimate tile (t = NT-2): stage only NT-1.h1; end fully drained.
#define TILE_PEN(BUF, kof1) do {                                              \
    DSA8(aY, BUF, 1);  DSB4(bY, BUF, 1);                                      \
    STA((BUF)^1, 1, kof1);  STB((BUF)^1, 1, kof1);                            \
    LGK(12);  MFM32(aX, bX);  CKPT(4);                                        \
    DSA8(aX, (BUF)^1, 0);  DSB4(bX, (BUF)^1, 0);                              \
    LGK(12);  MFM32(aY, bY);  CKPT(0);                                        \
} while (0)

// Last tile (t = NT-1): no staging, no barriers needed.
#define TILE_LAST(BUF) do {                                                   \
    DSA8(aY, BUF, 1);  DSB4(bY, BUF, 1);                                      \
    LGK(12);  MFM32(aX, bX);                                                  \
    LGK(0);   MFM32(aY, bY);                                                  \
} while (0)

    f32x4 acc[8][4];
    #pragma unroll
    for (int i = 0; i < 8; ++i)
        #pragma unroll
        for (int j = 0; j < 4; ++j)
            #pragma unroll
            for (int r = 0; r < 4; ++r) acc[i][j][r] = 0.0f;

    bf16x8 aX[8], aY[8], bX[4], bY[4];

    // prologue: stage t0.h0, t0.h1, t1.h0; read X <- t0.kk0.
    STA(0, 0, 0); STB(0, 0, 0);
    STA(0, 1, 0); STB(0, 1, 0);
    STA(1, 0, 64); STB(1, 0, 64);
    CKPT(8);                      // t0.h0 landed (all waves)
    DSA8(aX, 0, 0); DSB4(bX, 0, 0);
    CKPT(4);                      // t0.h1 landed (keep t1.h0 in flight)

    #pragma unroll 1
    for (int t = 0; t + 3 < NT; t += 2) {
        TILE_FULL(0, (long)(t + 1) * 64, (long)(t + 2) * 64);
        TILE_FULL(1, (long)(t + 2) * 64, (long)(t + 3) * 64);
    }
    TILE_PEN(0, (long)(NT - 1) * 64);
    TILE_LAST(1);

    // epilogue: C/D layout col = lane&15, row = (lane>>4)*4 + reg  [m89]
    const long crow0 = m0 + wm * 128;
    const long ccol0 = n0 + wn * 64;
    u16*   Cb = (u16*)Cout   + (long)bz * sC;
    float* Cf = (float*)Cout + (long)bz * sC;
    const float* resz = res + (long)bz * sR;
    #pragma unroll
    for (int i = 0; i < 8; ++i) {
        #pragma unroll
        for (int j = 0; j < 4; ++j) {
            const long col = ccol0 + j * 16 + lr;
            float bv_ = 0.0f;
            if (HAS_BIAS) bv_ = bias[col];
            if (OUT_MODE == 2) {
                const long row0 = crow0 + i * 16 + lk * 4;
                u16x4 pk;
                #pragma unroll
                for (int r = 0; r < 4; ++r) {
                    float v = acc[i][j][r] + bv_;
                    v *= scale;
                    pk[r] = f2b(v);
                }
                const long b_ = row0 >> 12, s_ = row0 & 4095;
                *(u16x4*)((u16*)Cout + (b_ << 22) + (col << 12) + s_) = pk;
            } else {
                #pragma unroll
                for (int r = 0; r < 4; ++r) {
                    const long row = crow0 + i * 16 + lk * 4 + r;
                    float v = acc[i][j][r];
                    if (HAS_BIAS) v += bv_;
                    v *= scale;
                    if (RELU) v = fmaxf(v, 0.0f);
                    if (HAS_RES) v += resz[row * (long)N + col];
                    if (OUT_MODE == 1) Cf[row * (long)N + col] = v;
                    else               Cb[row * (long)N + col] = f2b(v);
                }
            }
        }
    }
#undef STA
#undef STB
#undef DSA8
#undef DSB4
#undef LGK
#undef CKPT
#undef MFM32
#undef TILE_FULL
#undef TILE_PEN
#undef TILE_LAST
}

// distinct names per role for rocprof attribution ----------------------------
__global__ __launch_bounds__(512, 2) void g10_proj(
    const u16* A, const u16* Bt, const float* bias, u16* C, int N, int K)
{ gemm10_body<1,0,0,0>(A, Bt, bias, nullptr, C, N, K, 0,0,0,0, 1.0f); }

__global__ __launch_bounds__(512, 2) void g10_vproj(
    const u16* A, const u16* Bt, const float* bias, u16* C, int N, int K)
{ gemm10_body<1,0,0,2>(A, Bt, bias, nullptr, C, N, K, 0,0,0,0, 1.0f); }

__global__ __launch_bounds__(512, 2) void g10_qkt(
    const u16* A, const u16* Bt, u16* C, int N, int K,
    long sA, long sB, long sC, float scale)
{ gemm10_body<0,0,0,0>(A, Bt, nullptr, nullptr, C, N, K, sA, sB, sC, 0, scale); }

__global__ __launch_bounds__(512, 2) void g10_pv(
    const u16* A, const u16* Bt, const float* res, u16* C, int N, int K,
    long sA, long sB, long sC, long sR)
{ gemm10_body<0,0,1,0>(A, Bt, nullptr, res, C, N, K, sA, sB, sC, sR, 1.0f); }

__global__ __launch_bounds__(512, 2) void g10_ffn1(
    const u16* A, const u16* Bt, const float* bias, u16* C, int N, int K)
{ gemm10_body<1,1,0,0>(A, Bt, bias, nullptr, C, N, K, 0,0,0,0, 1.0f); }

__global__ __launch_bounds__(512, 2) void g10_ffn2(
    const u16* A, const u16* Bt, const float* bias, float* C, int N, int K, float scale)
{ gemm10_body<1,0,0,1>(A, Bt, bias, nullptr, C, N, K, 0,0,0,0, scale); }

// ---------------------------------------------------------------------------
__global__ __launch_bounds__(256) void cvt_f32_bf16(
    const float* __restrict__ in, u16* __restrict__ out, long n)
{
    long i = ((long)blockIdx.x * 256 + threadIdx.x) * 4;
    if (i >= n) return;
    float4 f = *(const float4*)(in + i);
    u16x4 o;
    o[0] = f2b(f.x); o[1] = f2b(f.y); o[2] = f2b(f.z); o[3] = f2b(f.w);
    *(u16x4*)(out + i) = o;
}

__global__ __launch_bounds__(256) void transpose_to_bf16(
    const float* __restrict__ in, u16* __restrict__ out, int R, int C)
{
    __shared__ float tile[32][33];
    const int bx = blockIdx.x * 32;
    const int by = blockIdx.y * 32;
    const int tx = threadIdx.x, ty = threadIdx.y;
    #pragma unroll
    for (int i = 0; i < 32; i += 8)
        tile[ty + i][tx] = in[(long)(by + ty + i) * C + bx + tx];
    __syncthreads();
    #pragma unroll
    for (int i = 0; i < 32; i += 8)
        out[(long)(bx + ty + i) * R + by + tx] = f2b(tile[tx][ty + i]);
}

// in-place row softmax over n=4096 bf16 elements; one block per row.
__global__ __launch_bounds__(256) void softmax_rows(u16* __restrict__ P, int n)
{
    const int t = threadIdx.x;
    const int lane = t & 63, w = t >> 6;
    u16* row = P + (long)blockIdx.x * n;
    u16x8 a = *(const u16x8*)(row + t * 16);
    u16x8 b = *(const u16x8*)(row + t * 16 + 8);
    float v[16];
    #pragma unroll
    for (int i = 0; i < 8; ++i) { v[i] = b2f(a[i]); v[8 + i] = b2f(b[i]); }

    float mx = v[0];
    #pragma unroll
    for (int i = 1; i < 16; ++i) mx = fmaxf(mx, v[i]);
    #pragma unroll
    for (int o = 32; o > 0; o >>= 1) mx = fmaxf(mx, __shfl_xor(mx, o));
    __shared__ float red[8];
    if (lane == 0) red[w] = mx;
    __syncthreads();
    mx = fmaxf(fmaxf(red[0], red[1]), fmaxf(red[2], red[3]));

    float s = 0.0f;
    #pragma unroll
    for (int i = 0; i < 16; ++i) { v[i] = __expf(v[i] - mx); s += v[i]; }
    #pragma unroll
    for (int o = 32; o > 0; o >>= 1) s += __shfl_xor(s, o);
    if (lane == 0) red[4 + w] = s;
    __syncthreads();
    s = red[4] + red[5] + red[6] + red[7];
    const float inv = 1.0f / s;

    #pragma unroll
    for (int i = 0; i < 8; ++i) { a[i] = f2b(v[i] * inv); b[i] = f2b(v[8 + i] * inv); }
    *(u16x8*)(row + t * 16)     = a;
    *(u16x8*)(row + t * 16 + 8) = b;
}

// ---------------------------------------------------------------------------
extern "C" void kernel_launch(void* const* d_in, const int* in_sizes, int n_in,
                              void* d_out, int out_size, void* d_ws, size_t ws_size,
                              hipStream_t stream)
{
    (void)in_sizes; (void)n_in; (void)out_size;
    const float* x  = (const float*)d_in[0];
    const float* Wq = (const float*)d_in[1];
    const float* bq = (const float*)d_in[2];
    const float* Wk = (const float*)d_in[3];
    const float* bk = (const float*)d_in[4];
    const float* Wv = (const float*)d_in[5];
    const float* bv = (const float*)d_in[6];
    const float* W1 = (const float*)d_in[7];
    const float* b1 = (const float*)d_in[8];
    const float* W2 = (const float*)d_in[9];
    const float* b2 = (const float*)d_in[10];
    float* out = (float*)d_out;

    const int  B = 4, S = 4096, D = 1024;
    const long SD  = (long)S * D;           // 4 Mi
    const long BSD = (long)B * SD;          // 16 Mi
    const long SS  = (long)S * S;           // 16 Mi

    // score-chunk size BC: P holds BC*SS elems, aliasing xb (dead after proj)
    int BC = 4;
    while (BC > 1 && (size_t)((long)BC * SS + 5L * D * D + 3L * BSD) * 2 > ws_size)
        BC >>= 1;

    // workspace layout (u16 elements)
    u16* Pb = (u16*)d_ws;            // [BC, S, S] scores; xb aliases Pb
    u16* xb = Pb;                    // [B*S, D] x bf16 (dead after proj)
    u16* Wt = Pb + (long)BC * SS;    // 5 x [D, D]
    u16* Qb = Wt + 5L * D * D;       // [B*S, D]   (later: h)
    u16* Kb = Qb + BSD;              // [B*S, D]   (later: x_res)
    u16* Vt = Kb + BSD;              // B x [D, S]

    cvt_f32_bf16<<<dim3((unsigned)(BSD / 4 / 256)), 256, 0, stream>>>(x, xb, BSD);

    dim3 tb(32, 8);
    transpose_to_bf16<<<dim3(D / 32, D / 32), tb, 0, stream>>>(Wq, Wt + 0L * D * D, D, D);
    transpose_to_bf16<<<dim3(D / 32, D / 32), tb, 0, stream>>>(Wk, Wt + 1L * D * D, D, D);
    transpose_to_bf16<<<dim3(D / 32, D / 32), tb, 0, stream>>>(Wv, Wt + 2L * D * D, D, D);
    transpose_to_bf16<<<dim3(D / 32, D / 32), tb, 0, stream>>>(W1, Wt + 3L * D * D, D, D);
    transpose_to_bf16<<<dim3(D / 32, D / 32), tb, 0, stream>>>(W2, Wt + 4L * D * D, D, D);

    const dim3 gproj(D / 256, (B * S) / 256);    // (4, 64) = 256 blocks
    g10_proj <<<gproj, 512, 0, stream>>>(xb, Wt + 0L*D*D, bq, Qb, D, D);
    g10_proj <<<gproj, 512, 0, stream>>>(xb, Wt + 1L*D*D, bk, Kb, D, D);
    g10_vproj<<<gproj, 512, 0, stream>>>(xb, Wt + 2L*D*D, bv, Vt, D, D);
    // xb is dead from here; Pb may overwrite it.

    for (int c = 0; c < B; c += BC) {
        g10_qkt<<<dim3(S/256, S/256, BC), 512, 0, stream>>>(
            Qb + (long)c * SD, Kb + (long)c * SD, Pb, S, D, SD, SD, SS, 0.03125f);
        softmax_rows<<<BC * S, 256, 0, stream>>>(Pb, S);
        g10_pv<<<dim3(D/256, S/256, BC), 512, 0, stream>>>(
            Pb, Vt + (long)c * SD, x + (long)c * SD, Kb + (long)c * SD,
            D, S, SS, SD, SD, SD);
    }

    // FFN: h = relu(x_res @ W1 + b1) -> Qb;  out = 2*(h @ W2 + b2) fp32
    g10_ffn1<<<gproj, 512, 0, stream>>>(Kb, Wt + 3L*D*D, b1, Qb, D, D);
    g10_ffn2<<<gproj, 512, 0, stream>>>(Qb, Wt + 4L*D*D, b2, out, D, D, 2.0f);
}

// Round 8
// 530.689 us; speedup vs baseline: 1.1109x; 1.1109x over previous
//
#include <hip/hip_runtime.h>
#include <stdint.h>

typedef unsigned short u16;
typedef __bf16 bf16x8 __attribute__((ext_vector_type(8)));
typedef float f32x4 __attribute__((ext_vector_type(4)));
typedef unsigned short u16x8 __attribute__((ext_vector_type(8)));
typedef unsigned short u16x4 __attribute__((ext_vector_type(4)));

__device__ __forceinline__ float b2f(u16 b) {
    return __uint_as_float(((unsigned)b) << 16);
}
__device__ __forceinline__ u16 f2b(float f) {
    unsigned u = __float_as_uint(f);
    unsigned r = (u + 0x7fffu + ((u >> 16) & 1u)) >> 16;  // RNE
    return (u16)r;
}

#define GLDS16(g, l) __builtin_amdgcn_global_load_lds(                        \
    (const __attribute__((address_space(1))) void*)(g),                       \
    (__attribute__((address_space(3))) void*)(l), 16, 0, 0)

// ---------------------------------------------------------------------------
// 256x256-tile register-pipelined GEMM (g9 structure) + chunk-XOR LDS
// swizzle.  C = epilogue(A @ Bt^T); A[M,K], Bt[N,K] bf16 row-major.
// 512 thr = 8 waves (2M x 4N); per-wave C = 128x64.  BK=64 as 2 K-halves,
// each [256 rows][4 chunks of 8 elems] (64B rows).
//
// SWIZZLE (T2 adapted to global_load_lds, rule 21): logical (row, chunk) is
// stored at physical chunk  chunk ^ ((row>>1)&3).  Involution; applied on
// BOTH sides:  staging thread tid (row=tid>>2, chunk=tid&3) fetches global
// chunk (tid&3)^((tid>>3)&3); fragment reads use lk ^ ((lr>>1)&3).
// Bank math: lane lr reads byte row*64 + chunk'*16 -> start bank-quad
// (row&1)*4 + chunk' = 8 distinct quads per 16-lane group, 2 lanes each =
// 2-way = free.  (Old layout: 2 quads -> 8-way conflict, 1.26e7 counter.)
//
// Schedule per K-tile (4 steps, reg pipeline 1 step ahead; 2 barriers):
//   see r6 ledger -- vmcnt(2) checkpoints, LGK(4|8) drains prev step only.
// OUT_MODE: 0 = bf16 [.,N], 1 = f32 [.,N], 2 = bf16 V^T scatter
//           (b = row>>12, Vt[b][col][row&4095], batch stride 1<<22).
// ---------------------------------------------------------------------------
template<int HAS_BIAS, int RELU, int HAS_RES, int OUT_MODE>
__device__ __forceinline__ void gemm11_body(
    const u16* __restrict__ A, const u16* __restrict__ Bt,
    const float* __restrict__ bias, const float* __restrict__ res,
    void* __restrict__ Cout, int N, int K,
    long sA, long sB, long sC, long sR, float scale)
{
    __shared__ u16 smem[65536];   // 128 KiB: A [buf][kk] 16KB x4, then B x4

    // chunked XCD swizzle (bijective; all grids here have nwg % 8 == 0)
    const long nwg = (long)gridDim.x * gridDim.y * gridDim.z;
    long gid = ((long)blockIdx.z * gridDim.y + blockIdx.y) * gridDim.x + blockIdx.x;
    long logical = (nwg % 8 == 0) ? (gid & 7) * (nwg >> 3) + (gid >> 3) : gid;
    const int bx = (int)(logical % gridDim.x);
    long tmp = logical / gridDim.x;
    const int by = (int)(tmp % gridDim.y);
    const int bz = (int)(tmp / gridDim.y);

    A  += (long)bz * sA;
    Bt += (long)bz * sB;

    const int tid  = threadIdx.x;
    const int lane = tid & 63, wid = tid >> 6;
    const int wm   = wid >> 2, wn = wid & 3;
    const int lr   = lane & 15, lk = lane >> 4;
    const long m0  = (long)by * 256;
    const long n0  = (long)bx * 256;
    const int  NT  = K >> 6;

    // staging source with inverse chunk swizzle: thread tid covers LDS slot
    // (row=tid>>2, chunk=tid&3); it must fetch logical chunk chunk^f(row),
    // f(row) = (row>>1)&3 = (tid>>3)&3.  (+128 rows keeps f unchanged.)
    const int sch = ((tid & 3) ^ ((tid >> 3) & 3)) * 8;
    const u16* gA0 = A  + (m0 + (tid >> 2)) * (long)K + sch;
    const u16* gB0 = Bt + (n0 + (tid >> 2)) * (long)K + sch;
    const u16* gA1 = gA0 + 128L * K;
    const u16* gB1 = gB0 + 128L * K;
    const int wdst = (tid & ~63) * 8;   // u16 elems

#define STA(bufn, kk, kof) do {                                               \
    GLDS16(gA0 + (kof) + (kk) * 32, &smem[(bufn)*16384 + (kk)*8192 + wdst]);  \
    GLDS16(gA1 + (kof) + (kk) * 32, &smem[(bufn)*16384 + (kk)*8192 + wdst + 4096]); } while (0)
#define STB(bufn, kk, kof) do {                                               \
    GLDS16(gB0 + (kof) + (kk) * 32, &smem[32768 + (bufn)*16384 + (kk)*8192 + wdst]); \
    GLDS16(gB1 + (kof) + (kk) * 32, &smem[32768 + (bufn)*16384 + (kk)*8192 + wdst + 4096]); } while (0)

    // fragment reads: chunk swizzled by lkA = lk ^ ((lr>>1)&3); row offsets
    // added per-frag are multiples of 16 rows so f(row) stays (lr>>1)&3.
    const int lkA   = lk ^ ((lr >> 1) & 3);
    const int raOff = (wm * 128 + lr) * 32 + lkA * 8;   // + i*512 per A-frag
    const int rbOff = (wn * 64  + lr) * 32 + lkA * 8;   // + j*512 per B-frag

#define DSA(dst, BUF, kk, ih) do { _Pragma("unroll")                          \
    for (int i = 0; i < 4; ++i)                                               \
        dst[i] = *(const bf16x8*)&smem[(BUF)*16384 + (kk)*8192 + raOff + ((ih)*4 + i)*512]; } while (0)
#define DSB(dst, BUF, kk) do { _Pragma("unroll")                              \
    for (int j = 0; j < 4; ++j)                                               \
        dst[j] = *(const bf16x8*)&smem[32768 + (BUF)*16384 + (kk)*8192 + rbOff + j*512]; } while (0)

#define LGK(n) do { asm volatile("s_waitcnt lgkmcnt(" #n ")" ::: "memory");   \
                    __builtin_amdgcn_sched_barrier(0); } while (0)
#define CKPT(n) do { asm volatile("s_waitcnt vmcnt(" #n ")" ::: "memory");    \
    __builtin_amdgcn_s_barrier(); __builtin_amdgcn_sched_barrier(0); } while (0)

#define MFM(IH, A_, B_) do { __builtin_amdgcn_s_setprio(1); _Pragma("unroll") \
    for (int i = 0; i < 4; ++i) _Pragma("unroll")                             \
        for (int j = 0; j < 4; ++j)                                           \
            acc[(IH)*4 + i][j] = __builtin_amdgcn_mfma_f32_16x16x32_bf16(     \
                A_[i], B_[j], acc[(IH)*4 + i][j], 0, 0, 0);                   \
    __builtin_amdgcn_s_setprio(0); } while (0)

// One K-tile in buffer BUF, staging tile at k-offset kof into BUF^1.
// Entry: aX = a(BUF,kk0,ih0), bX = b(BUF,kk0) already in regs.
// Exit: aX,bX = next tile's kk0 frags (reads in flight).
#define TILE_MAIN(BUF, kof) do {                                              \
    DSA(aY, BUF, 0, 1);                 STA((BUF)^1, 0, kof);                 \
    LGK(4);  MFM(0, aX, bX);                                                  \
    CKPT(2);                                                                  \
    DSA(aX, BUF, 1, 0);  DSB(bY, BUF, 1);  STB((BUF)^1, 0, kof);              \
    LGK(8);  MFM(1, aY, bX);                                                  \
    DSA(aY, BUF, 1, 1);                 STA((BUF)^1, 1, kof);                 \
    LGK(4);  MFM(0, aX, bY);                                                  \
    CKPT(2);                                                                  \
    DSA(aX, (BUF)^1, 0, 0);  DSB(bX, (BUF)^1, 0);  STB((BUF)^1, 1, kof);      \
    LGK(8);  MFM(1, aY, bY);                                                  \
} while (0)

#define TILE_LAST(BUF) do {                                                   \
    DSA(aY, BUF, 0, 1);                                                       \
    LGK(4);  MFM(0, aX, bX);                                                  \
    CKPT(0);                                                                  \
    DSA(aX, BUF, 1, 0);  DSB(bY, BUF, 1);                                     \
    LGK(8);  MFM(1, aY, bX);                                                  \
    DSA(aY, BUF, 1, 1);                                                       \
    LGK(4);  MFM(0, aX, bY);                                                  \
    LGK(0);  MFM(1, aY, bY);                                                  \
} while (0)

    f32x4 acc[8][4];
    #pragma unroll
    for (int i = 0; i < 8; ++i)
        #pragma unroll
        for (int j = 0; j < 4; ++j)
            #pragma unroll
            for (int r = 0; r < 4; ++r) acc[i][j][r] = 0.0f;

    bf16x8 aX[4], aY[4], bX[4], bY[4];

    // prologue: stage tile 0; wait A0,B0 halves; preload step-0 fragments.
    STA(0, 0, 0); STB(0, 0, 0); STA(0, 1, 0); STB(0, 1, 0);
    CKPT(4);
    DSA(aX, 0, 0, 0); DSB(bX, 0, 0);

    #pragma unroll 1
    for (int t = 0; t + 2 < NT; t += 2) {
        TILE_MAIN(0, (long)(t + 1) * 64);
        TILE_MAIN(1, (long)(t + 2) * 64);
    }
    TILE_MAIN(0, (long)(NT - 1) * 64);
    TILE_LAST(1);

    // epilogue: C/D layout col = lane&15, row = (lane>>4)*4 + reg  [m89]
    const long crow0 = m0 + wm * 128;
    const long ccol0 = n0 + wn * 64;
    u16*   Cb = (u16*)Cout   + (long)bz * sC;
    float* Cf = (float*)Cout + (long)bz * sC;
    const float* resz = res + (long)bz * sR;
    #pragma unroll
    for (int i = 0; i < 8; ++i) {
        #pragma unroll
        for (int j = 0; j < 4; ++j) {
            const long col = ccol0 + j * 16 + lr;
            float bv_ = 0.0f;
            if (HAS_BIAS) bv_ = bias[col];
            if (OUT_MODE == 2) {
                const long row0 = crow0 + i * 16 + lk * 4;
                u16x4 pk;
                #pragma unroll
                for (int r = 0; r < 4; ++r) {
                    float v = acc[i][j][r] + bv_;
                    v *= scale;
                    pk[r] = f2b(v);
                }
                const long b_ = row0 >> 12, s_ = row0 & 4095;
                *(u16x4*)((u16*)Cout + (b_ << 22) + (col << 12) + s_) = pk;
            } else {
                #pragma unroll
                for (int r = 0; r < 4; ++r) {
                    const long row = crow0 + i * 16 + lk * 4 + r;
                    float v = acc[i][j][r];
                    if (HAS_BIAS) v += bv_;
                    v *= scale;
                    if (RELU) v = fmaxf(v, 0.0f);
                    if (HAS_RES) v += resz[row * (long)N + col];
                    if (OUT_MODE == 1) Cf[row * (long)N + col] = v;
                    else               Cb[row * (long)N + col] = f2b(v);
                }
            }
        }
    }
#undef STA
#undef STB
#undef DSA
#undef DSB
#undef LGK
#undef CKPT
#undef MFM
#undef TILE_MAIN
#undef TILE_LAST
}

// distinct names per role for rocprof attribution ----------------------------
__global__ __launch_bounds__(512, 2) void g11_proj(
    const u16* A, const u16* Bt, const float* bias, u16* C, int N, int K)
{ gemm11_body<1,0,0,0>(A, Bt, bias, nullptr, C, N, K, 0,0,0,0, 1.0f); }

__global__ __launch_bounds__(512, 2) void g11_vproj(
    const u16* A, const u16* Bt, const float* bias, u16* C, int N, int K)
{ gemm11_body<1,0,0,2>(A, Bt, bias, nullptr, C, N, K, 0,0,0,0, 1.0f); }

__global__ __launch_bounds__(512, 2) void g11_qkt(
    const u16* A, const u16* Bt, u16* C, int N, int K,
    long sA, long sB, long sC, float scale)
{ gemm11_body<0,0,0,0>(A, Bt, nullptr, nullptr, C, N, K, sA, sB, sC, 0, scale); }

__global__ __launch_bounds__(512, 2) void g11_pv(
    const u16* A, const u16* Bt, const float* res, u16* C, int N, int K,
    long sA, long sB, long sC, long sR)
{ gemm11_body<0,0,1,0>(A, Bt, nullptr, res, C, N, K, sA, sB, sC, sR, 1.0f); }

__global__ __launch_bounds__(512, 2) void g11_ffn1(
    const u16* A, const u16* Bt, const float* bias, u16* C, int N, int K)
{ gemm11_body<1,1,0,0>(A, Bt, bias, nullptr, C, N, K, 0,0,0,0, 1.0f); }

__global__ __launch_bounds__(512, 2) void g11_ffn2(
    const u16* A, const u16* Bt, const float* bias, float* C, int N, int K, float scale)
{ gemm11_body<1,0,0,1>(A, Bt, bias, nullptr, C, N, K, 0,0,0,0, scale); }

// ---------------------------------------------------------------------------
__global__ __launch_bounds__(256) void cvt_f32_bf16(
    const float* __restrict__ in, u16* __restrict__ out, long n)
{
    long i = ((long)blockIdx.x * 256 + threadIdx.x) * 4;
    if (i >= n) return;
    float4 f = *(const float4*)(in + i);
    u16x4 o;
    o[0] = f2b(f.x); o[1] = f2b(f.y); o[2] = f2b(f.z); o[3] = f2b(f.w);
    *(u16x4*)(out + i) = o;
}

__global__ __launch_bounds__(256) void transpose_to_bf16(
    const float* __restrict__ in, u16* __restrict__ out, int R, int C)
{
    __shared__ float tile[32][33];
    const int bx = blockIdx.x * 32;
    const int by = blockIdx.y * 32;
    const int tx = threadIdx.x, ty = threadIdx.y;
    #pragma unroll
    for (int i = 0; i < 32; i += 8)
        tile[ty + i][tx] = in[(long)(by + ty + i) * C + bx + tx];
    __syncthreads();
    #pragma unroll
    for (int i = 0; i < 32; i += 8)
        out[(long)(bx + ty + i) * R + by + tx] = f2b(tile[tx][ty + i]);
}

// in-place row softmax over n=4096 bf16 elements; one block per row.
__global__ __launch_bounds__(256) void softmax_rows(u16* __restrict__ P, int n)
{
    const int t = threadIdx.x;
    const int lane = t & 63, w = t >> 6;
    u16* row = P + (long)blockIdx.x * n;
    u16x8 a = *(const u16x8*)(row + t * 16);
    u16x8 b = *(const u16x8*)(row + t * 16 + 8);
    float v[16];
    #pragma unroll
    for (int i = 0; i < 8; ++i) { v[i] = b2f(a[i]); v[8 + i] = b2f(b[i]); }

    float mx = v[0];
    #pragma unroll
    for (int i = 1; i < 16; ++i) mx = fmaxf(mx, v[i]);
    #pragma unroll
    for (int o = 32; o > 0; o >>= 1) mx = fmaxf(mx, __shfl_xor(mx, o));
    __shared__ float red[8];
    if (lane == 0) red[w] = mx;
    __syncthreads();
    mx = fmaxf(fmaxf(red[0], red[1]), fmaxf(red[2], red[3]));

    float s = 0.0f;
    #pragma unroll
    for (int i = 0; i < 16; ++i) { v[i] = __expf(v[i] - mx); s += v[i]; }
    #pragma unroll
    for (int o = 32; o > 0; o >>= 1) s += __shfl_xor(s, o);
    if (lane == 0) red[4 + w] = s;
    __syncthreads();
    s = red[4] + red[5] + red[6] + red[7];
    const float inv = 1.0f / s;

    #pragma unroll
    for (int i = 0; i < 8; ++i) { a[i] = f2b(v[i] * inv); b[i] = f2b(v[8 + i] * inv); }
    *(u16x8*)(row + t * 16)     = a;
    *(u16x8*)(row + t * 16 + 8) = b;
}

// ---------------------------------------------------------------------------
extern "C" void kernel_launch(void* const* d_in, const int* in_sizes, int n_in,
                              void* d_out, int out_size, void* d_ws, size_t ws_size,
                              hipStream_t stream)
{
    (void)in_sizes; (void)n_in; (void)out_size;
    const float* x  = (const float*)d_in[0];
    const float* Wq = (const float*)d_in[1];
    const float* bq = (const float*)d_in[2];
    const float* Wk = (const float*)d_in[3];
    const float* bk = (const float*)d_in[4];
    const float* Wv = (const float*)d_in[5];
    const float* bv = (const float*)d_in[6];
    const float* W1 = (const float*)d_in[7];
    const float* b1 = (const float*)d_in[8];
    const float* W2 = (const float*)d_in[9];
    const float* b2 = (const float*)d_in[10];
    float* out = (float*)d_out;

    const int  B = 4, S = 4096, D = 1024;
    const long SD  = (long)S * D;           // 4 Mi
    const long BSD = (long)B * SD;          // 16 Mi
    const long SS  = (long)S * S;           // 16 Mi

    // score-chunk size BC: P holds BC*SS elems, aliasing xb (dead after proj)
    int BC = 4;
    while (BC > 1 && (size_t)((long)BC * SS + 5L * D * D + 3L * BSD) * 2 > ws_size)
        BC >>= 1;

    // workspace layout (u16 elements)
    u16* Pb = (u16*)d_ws;            // [BC, S, S] scores; xb aliases Pb
    u16* xb = Pb;                    // [B*S, D] x bf16 (dead after proj)
    u16* Wt = Pb + (long)BC * SS;    // 5 x [D, D]
    u16* Qb = Wt + 5L * D * D;       // [B*S, D]   (later: h)
    u16* Kb = Qb + BSD;              // [B*S, D]   (later: x_res)
    u16* Vt = Kb + BSD;              // B x [D, S]

    cvt_f32_bf16<<<dim3((unsigned)(BSD / 4 / 256)), 256, 0, stream>>>(x, xb, BSD);

    dim3 tb(32, 8);
    transpose_to_bf16<<<dim3(D / 32, D / 32), tb, 0, stream>>>(Wq, Wt + 0L * D * D, D, D);
    transpose_to_bf16<<<dim3(D / 32, D / 32), tb, 0, stream>>>(Wk, Wt + 1L * D * D, D, D);
    transpose_to_bf16<<<dim3(D / 32, D / 32), tb, 0, stream>>>(Wv, Wt + 2L * D * D, D, D);
    transpose_to_bf16<<<dim3(D / 32, D / 32), tb, 0, stream>>>(W1, Wt + 3L * D * D, D, D);
    transpose_to_bf16<<<dim3(D / 32, D / 32), tb, 0, stream>>>(W2, Wt + 4L * D * D, D, D);

    const dim3 gproj(D / 256, (B * S) / 256);    // (4, 64) = 256 blocks
    g11_proj <<<gproj, 512, 0, stream>>>(xb, Wt + 0L*D*D, bq, Qb, D, D);
    g11_proj <<<gproj, 512, 0, stream>>>(xb, Wt + 1L*D*D, bk, Kb, D, D);
    g11_vproj<<<gproj, 512, 0, stream>>>(xb, Wt + 2L*D*D, bv, Vt, D, D);
    // xb is dead from here; Pb may overwrite it.

    for (int c = 0; c < B; c += BC) {
        g11_qkt<<<dim3(S/256, S/256, BC), 512, 0, stream>>>(
            Qb + (long)c * SD, Kb + (long)c * SD, Pb, S, D, SD, SD, SS, 0.03125f);
        softmax_rows<<<BC * S, 256, 0, stream>>>(Pb, S);
        g11_pv<<<dim3(D/256, S/256, BC), 512, 0, stream>>>(
            Pb, Vt + (long)c * SD, x + (long)c * SD, Kb + (long)c * SD,
            D, S, SS, SD, SD, SD);
    }

    // FFN: h = relu(x_res @ W1 + b1) -> Qb;  out = 2*(h @ W2 + b2) fp32
    g11_ffn1<<<gproj, 512, 0, stream>>>(Kb, Wt + 3L*D*D, b1, Qb, D, D);
    g11_ffn2<<<gproj, 512, 0, stream>>>(Qb, Wt + 4L*D*D, b2, out, D, D, 2.0f);
}